// Round 4
// baseline (397.654 us; speedup 1.0000x reference)
//
#include <hip/hip_runtime.h>
#include <hip/hip_bf16.h>
#include <math.h>

#define N_NODES 50000
#define N_HYPER 20000
#define N_EDGES_C 1000000
#define N_REL 256
#define DIM 128
#define SEM_DIM 64
#define CAP 128   // max edges per bucket; mean=50, sigma~7 -> ~11 sigma headroom

__device__ inline float half_sum32(float v) {
#pragma unroll
  for (int m = 1; m < 32; m <<= 1) v += __shfl_xor(v, m, 64);
  return v;
}

// sem_t[r][j] = sem_b[j] + sum_k emb[r][k] * sem_w[j][k]
__global__ __launch_bounds__(128) void k_sem(const float* __restrict__ emb,
                                             const float* __restrict__ sem_w,
                                             const float* __restrict__ sem_b,
                                             float* __restrict__ sem_t) {
  __shared__ float sW[DIM][SEM_DIM + 1];
  __shared__ float sE[SEM_DIM];
  int t = threadIdx.x;
  for (int i = t; i < DIM * SEM_DIM; i += 128) sW[i / SEM_DIM][i % SEM_DIM] = sem_w[i];
  int r = blockIdx.x;
  if (t < SEM_DIM) sE[t] = emb[r * SEM_DIM + t];
  __syncthreads();
  float acc = sem_b[t];
#pragma unroll 8
  for (int k = 0; k < SEM_DIM; ++k) acc = fmaf(sE[k], sW[t][k], acc);
  sem_t[r * DIM + t] = acc;
}

// C[M x 128] = X[M x 128] @ W[128 x 128]
#define GBM 64
__global__ __launch_bounds__(256) void k_gemm128(const float* __restrict__ X,
                                                 const float* __restrict__ W,
                                                 float* __restrict__ C, int M) {
  __shared__ float sX[GBM][DIM];
  int t = threadIdx.x;
  long bm = (long)blockIdx.x * GBM;
  int rows = min(GBM, M - (int)bm);
  {
    const float4* Xv = (const float4*)(X + bm * DIM);
    float4* sXv = (float4*)&sX[0][0];
    int n4 = rows * DIM / 4;
    for (int i = t; i < n4; i += 256) sXv[i] = Xv[i];
  }
  __syncthreads();
  int c = t & 31;
  int r0 = (t >> 5) * 8;
  float acc[8][4] = {};
  for (int k = 0; k < DIM; k += 4) {
    float4 xr[8];
#pragma unroll
    for (int i = 0; i < 8; ++i) xr[i] = *(const float4*)&sX[r0 + i][k];
#pragma unroll
    for (int kk = 0; kk < 4; ++kk) {
      float w0 = W[(k + kk) * DIM + c];
      float w1 = W[(k + kk) * DIM + c + 32];
      float w2 = W[(k + kk) * DIM + c + 64];
      float w3 = W[(k + kk) * DIM + c + 96];
#pragma unroll
      for (int i = 0; i < 8; ++i) {
        float x = (&xr[i].x)[kk];
        acc[i][0] = fmaf(x, w0, acc[i][0]);
        acc[i][1] = fmaf(x, w1, acc[i][1]);
        acc[i][2] = fmaf(x, w2, acc[i][2]);
        acc[i][3] = fmaf(x, w3, acc[i][3]);
      }
    }
  }
  for (int i = 0; i < 8; ++i) {
    int r = r0 + i;
    if (r < rows) {
      float* Cr = C + (bm + r) * DIM;
      Cr[c] = acc[i][0]; Cr[c + 32] = acc[i][1];
      Cr[c + 64] = acc[i][2]; Cr[c + 96] = acc[i][3];
    }
  }
}

// bucket scatter: pos = cnt[h]++, ed[h*CAP+pos] = (node, rel)
__global__ void k_scatter(const int* __restrict__ sl, int* __restrict__ cnt,
                          int2* __restrict__ ed) {
  int stride = gridDim.x * blockDim.x;
  for (int e = blockIdx.x * blockDim.x + threadIdx.x; e < N_EDGES_C; e += stride) {
    int node = sl[3 * e + 0];
    int h = sl[3 * e + 1];
    int rel = sl[3 * e + 2];
    int pos = atomicAdd(&cnt[h], 1);
    if (pos < CAP) ed[(size_t)h * CAP + pos] = make_int2(node, rel);
  }
}

// one wave per hyperedge; 8 groups x 8 lanes; each group owns one edge per
// round, each lane owns 16 dims. No softmax-max (scores bounded << 88).
#define NG 8
__global__ __launch_bounds__(256) void k_agg(
    const float* __restrict__ rh, const float* __restrict__ rt,
    const float* __restrict__ semt, const float* __restrict__ node_emb,
    const int2* __restrict__ ed, const int* __restrict__ cnt,
    float* __restrict__ agg) {
  int wave = threadIdx.x >> 6;
  int lane = threadIdx.x & 63;
  int h = blockIdx.x * 4 + wave;
  int g = lane >> 3;        // group 0..7 = edge slot
  int pos = lane & 7;       // dim chunk: dims [pos*16, pos*16+16)
  int d0 = pos * 16;
  const float4* tbp = (const float4*)&rt[(size_t)h * DIM + d0];
  float4 tb0 = tbp[0], tb1 = tbp[1], tb2 = tbp[2], tb3 = tbp[3];
  size_t base = (size_t)h * CAP;
  int n = min(cnt[h], CAP);
  float l = 0.0f;
  float4 a0 = {0,0,0,0}, a1 = {0,0,0,0}, a2 = {0,0,0,0}, a3 = {0,0,0,0};
  const float C2 = 2.8853900817779268f;  // 2*log2(e)

  for (int e = g; e < n; e += NG) {
    int2 q = ed[base + e];
    const float4* sp = (const float4*)&semt[(size_t)q.y * DIM + d0];
    const float4* hp = (const float4*)&rh[(size_t)q.x * DIM + d0];
    const float4* np = (const float4*)&node_emb[(size_t)q.x * DIM + d0];
    float4 s0 = sp[0], s1 = sp[1], s2 = sp[2], s3 = sp[3];
    float4 h0 = hp[0], h1 = hp[1], h2 = hp[2], h3 = hp[3];
    float4 n0 = np[0], n1 = np[1], n2 = np[2], n3 = np[3];
    // tanh(tb+s) dot h, 4 independent partial accumulators
    float d0a = 0.f, d1a = 0.f, d2a = 0.f, d3a = 0.f;
#define TDOT(acc, T, S, H, c)                                        \
    {                                                                \
      float xx = T.c + S.c;                                          \
      float ee = exp2f(xx * C2);                                     \
      float rr = __builtin_amdgcn_rcpf(ee + 1.0f);                   \
      float tt = fmaf(-2.0f, rr, 1.0f);                              \
      acc = fmaf(H.c, tt, acc);                                      \
    }
    TDOT(d0a, tb0, s0, h0, x) TDOT(d1a, tb0, s0, h0, y)
    TDOT(d2a, tb0, s0, h0, z) TDOT(d3a, tb0, s0, h0, w)
    TDOT(d0a, tb1, s1, h1, x) TDOT(d1a, tb1, s1, h1, y)
    TDOT(d2a, tb1, s1, h1, z) TDOT(d3a, tb1, s1, h1, w)
    TDOT(d0a, tb2, s2, h2, x) TDOT(d1a, tb2, s2, h2, y)
    TDOT(d2a, tb2, s2, h2, z) TDOT(d3a, tb2, s2, h2, w)
    TDOT(d0a, tb3, s3, h3, x) TDOT(d1a, tb3, s3, h3, y)
    TDOT(d2a, tb3, s3, h3, z) TDOT(d3a, tb3, s3, h3, w)
#undef TDOT
    float dot = (d0a + d1a) + (d2a + d3a);
    // reduce across the 8 lanes of this group (all groups share the insts)
    dot += __shfl_xor(dot, 1, 64);
    dot += __shfl_xor(dot, 2, 64);
    dot += __shfl_xor(dot, 4, 64);
    float p = __expf(dot);
    l += p;
    a0.x = fmaf(p, n0.x, a0.x); a0.y = fmaf(p, n0.y, a0.y);
    a0.z = fmaf(p, n0.z, a0.z); a0.w = fmaf(p, n0.w, a0.w);
    a1.x = fmaf(p, n1.x, a1.x); a1.y = fmaf(p, n1.y, a1.y);
    a1.z = fmaf(p, n1.z, a1.z); a1.w = fmaf(p, n1.w, a1.w);
    a2.x = fmaf(p, n2.x, a2.x); a2.y = fmaf(p, n2.y, a2.y);
    a2.z = fmaf(p, n2.z, a2.z); a2.w = fmaf(p, n2.w, a2.w);
    a3.x = fmaf(p, n3.x, a3.x); a3.y = fmaf(p, n3.y, a3.y);
    a3.z = fmaf(p, n3.z, a3.z); a3.w = fmaf(p, n3.w, a3.w);
  }
  // merge the 8 groups (lane bits 3,4,5): 17 values x 3 xor steps
#pragma unroll
  for (int mo = 8; mo < 64; mo <<= 1) {
    l += __shfl_xor(l, mo, 64);
    a0.x += __shfl_xor(a0.x, mo, 64); a0.y += __shfl_xor(a0.y, mo, 64);
    a0.z += __shfl_xor(a0.z, mo, 64); a0.w += __shfl_xor(a0.w, mo, 64);
    a1.x += __shfl_xor(a1.x, mo, 64); a1.y += __shfl_xor(a1.y, mo, 64);
    a1.z += __shfl_xor(a1.z, mo, 64); a1.w += __shfl_xor(a1.w, mo, 64);
    a2.x += __shfl_xor(a2.x, mo, 64); a2.y += __shfl_xor(a2.y, mo, 64);
    a2.z += __shfl_xor(a2.z, mo, 64); a2.w += __shfl_xor(a2.w, mo, 64);
    a3.x += __shfl_xor(a3.x, mo, 64); a3.y += __shfl_xor(a3.y, mo, 64);
    a3.z += __shfl_xor(a3.z, mo, 64); a3.w += __shfl_xor(a3.w, mo, 64);
  }
  if (g == 0) {
    float inv = (l > 0.0f) ? __builtin_amdgcn_rcpf(l) : 0.0f;
    float4* op = (float4*)&agg[(size_t)h * DIM + d0];
    float4 o0 = {a0.x * inv, a0.y * inv, a0.z * inv, a0.w * inv};
    float4 o1 = {a1.x * inv, a1.y * inv, a1.z * inv, a1.w * inv};
    float4 o2 = {a2.x * inv, a2.y * inv, a2.z * inv, a2.w * inv};
    float4 o3 = {a3.x * inv, a3.y * inv, a3.z * inv, a3.w * inv};
    op[0] = o0; op[1] = o1; op[2] = o2; op[3] = o3;
  }
}

__global__ void k_transpose128(const float* __restrict__ A, float* __restrict__ B) {
  int i = blockIdx.x * blockDim.x + threadIdx.x;
  if (i < DIM * DIM) {
    int j = i / DIM, k = i % DIM;
    B[k * DIM + j] = A[i];
  }
}

// fused: C = X @ W; out = LN(leakyrelu(C + bias)) * gamma + beta
__global__ __launch_bounds__(256) void k_gemm_ln(
    const float* __restrict__ X, const float* __restrict__ W,
    const float* __restrict__ bias, const float* __restrict__ gamma,
    const float* __restrict__ beta, float* __restrict__ out, int M) {
  __shared__ float sX[GBM][DIM];
  int t = threadIdx.x;
  long bm = (long)blockIdx.x * GBM;
  int rows = min(GBM, M - (int)bm);
  {
    const float4* Xv = (const float4*)(X + bm * DIM);
    float4* sXv = (float4*)&sX[0][0];
    int n4 = rows * DIM / 4;
    for (int i = t; i < n4; i += 256) sXv[i] = Xv[i];
  }
  __syncthreads();
  int c = t & 31;
  int r0 = (t >> 5) * 8;
  float acc[8][4] = {};
  for (int k = 0; k < DIM; k += 4) {
    float4 xr[8];
#pragma unroll
    for (int i = 0; i < 8; ++i) xr[i] = *(const float4*)&sX[r0 + i][k];
#pragma unroll
    for (int kk = 0; kk < 4; ++kk) {
      float w0 = W[(k + kk) * DIM + c];
      float w1 = W[(k + kk) * DIM + c + 32];
      float w2 = W[(k + kk) * DIM + c + 64];
      float w3 = W[(k + kk) * DIM + c + 96];
#pragma unroll
      for (int i = 0; i < 8; ++i) {
        float x = (&xr[i].x)[kk];
        acc[i][0] = fmaf(x, w0, acc[i][0]);
        acc[i][1] = fmaf(x, w1, acc[i][1]);
        acc[i][2] = fmaf(x, w2, acc[i][2]);
        acc[i][3] = fmaf(x, w3, acc[i][3]);
      }
    }
  }
  float b0 = bias[c], b1 = bias[c + 32], b2 = bias[c + 64], b3 = bias[c + 96];
  float g0 = gamma[c], g1 = gamma[c + 32], g2 = gamma[c + 64], g3 = gamma[c + 96];
  float e0 = beta[c], e1 = beta[c + 32], e2 = beta[c + 64], e3 = beta[c + 96];
#pragma unroll
  for (int i = 0; i < 8; ++i) {
    float v0 = acc[i][0] + b0, v1 = acc[i][1] + b1;
    float v2 = acc[i][2] + b2, v3 = acc[i][3] + b3;
    v0 = v0 >= 0.0f ? v0 : 0.01f * v0;
    v1 = v1 >= 0.0f ? v1 : 0.01f * v1;
    v2 = v2 >= 0.0f ? v2 : 0.01f * v2;
    v3 = v3 >= 0.0f ? v3 : 0.01f * v3;
    float mu = half_sum32(v0 + v1 + v2 + v3) * (1.0f / 128.0f);
    float d0 = v0 - mu, d1 = v1 - mu, d2 = v2 - mu, d3 = v3 - mu;
    float var = half_sum32(d0 * d0 + d1 * d1 + d2 * d2 + d3 * d3) * (1.0f / 128.0f);
    float inv = rsqrtf(var + 1e-5f);
    int r = r0 + i;
    if (r < rows) {
      float* Or = out + (bm + r) * DIM;
      Or[c] = d0 * inv * g0 + e0;
      Or[c + 32] = d1 * inv * g1 + e1;
      Or[c + 64] = d2 * inv * g2 + e2;
      Or[c + 96] = d3 * inv * g3 + e3;
    }
  }
}

extern "C" void kernel_launch(void* const* d_in, const int* in_sizes, int n_in,
                              void* d_out, int out_size, void* d_ws, size_t ws_size,
                              hipStream_t stream) {
  const float* node_emb = (const float*)d_in[0];
  const float* sem_emb = (const float*)d_in[1];
  const float* hyper_emb = (const float*)d_in[2];
  const float* W_r = (const float*)d_in[3];
  const float* lin_w = (const float*)d_in[4];
  const float* lin_b = (const float*)d_in[5];
  const float* sem_w = (const float*)d_in[6];
  const float* sem_b = (const float*)d_in[7];
  const float* ln_g = (const float*)d_in[8];
  const float* ln_b = (const float*)d_in[9];
  const int* sl = (const int*)d_in[10];
  float* out = (float*)d_out;

  float* ws = (float*)d_ws;
  float* sem_t = ws;                       // 32768
  float* rh = sem_t + 32768;               // 6,400,000
  float* rt = rh + 6400000;                // 2,560,000
  float* aggb = rt + 2560000;              // 2,560,000
  float* linwT = aggb + 2560000;           // 16,384
  int* cnt = (int*)(linwT + 16384);        // 20,000
  int2* ed = (int2*)(cnt + 20000);         // 20000*128 int2

  hipMemsetAsync(cnt, 0, sizeof(int) * 20000, stream);
  k_sem<<<N_REL, 128, 0, stream>>>(sem_emb, sem_w, sem_b, sem_t);
  k_gemm128<<<(N_NODES + GBM - 1) / GBM, 256, 0, stream>>>(node_emb, W_r, rh, N_NODES);
  k_gemm128<<<(N_HYPER + GBM - 1) / GBM, 256, 0, stream>>>(hyper_emb, W_r, rt, N_HYPER);
  k_scatter<<<2048, 256, 0, stream>>>(sl, cnt, ed);
  k_agg<<<N_HYPER / 4, 256, 0, stream>>>(rh, rt, sem_t, node_emb, ed, cnt, aggb);
  k_transpose128<<<64, 256, 0, stream>>>(lin_w, linwT);
  k_gemm_ln<<<(N_HYPER + GBM - 1) / GBM, 256, 0, stream>>>(aggb, linwT, lin_b, ln_g, ln_b, out, N_HYPER);
}

// Round 6
// 323.991 us; speedup vs baseline: 1.2274x; 1.2274x over previous
//
#include <hip/hip_runtime.h>
#include <hip/hip_bf16.h>
#include <hip/hip_fp16.h>
#include <math.h>

#define N_NODES 50000
#define N_HYPER 20000
#define N_EDGES_C 1000000
#define N_REL 256
#define DIM 128
#define SEM_DIM 64
#define CAP 128   // max edges per bucket; mean=50, sigma~7 -> ~11 sigma headroom

typedef unsigned int uint;
typedef unsigned short ushort;

__device__ inline float half_sum32(float v) {
#pragma unroll
  for (int m = 1; m < 32; m <<= 1) v += __shfl_xor(v, m, 64);
  return v;
}

__device__ inline ushort f16rn(float f) { return __half_as_ushort(__float2half_rn(f)); }
__device__ inline float f16lo(uint u) { return __half2float(__ushort_as_half((ushort)(u & 0xffffu))); }
__device__ inline float f16hi(uint u) { return __half2float(__ushort_as_half((ushort)(u >> 16))); }

// sem_t_h[r][j] = fp16(sem_b[j] + sum_k emb[r][k] * sem_w[j][k])
__global__ __launch_bounds__(128) void k_sem(const float* __restrict__ emb,
                                             const float* __restrict__ sem_w,
                                             const float* __restrict__ sem_b,
                                             ushort* __restrict__ sem_t_h) {
  __shared__ float sW[DIM][SEM_DIM + 1];
  __shared__ float sE[SEM_DIM];
  int t = threadIdx.x;
  for (int i = t; i < DIM * SEM_DIM; i += 128) sW[i / SEM_DIM][i % SEM_DIM] = sem_w[i];
  int r = blockIdx.x;
  if (t < SEM_DIM) sE[t] = emb[r * SEM_DIM + t];
  __syncthreads();
  float acc = sem_b[t];
#pragma unroll 8
  for (int k = 0; k < SEM_DIM; ++k) acc = fmaf(sE[k], sW[t][k], acc);
  sem_t_h[r * DIM + t] = f16rn(acc);
}

// C[M x 128] = X[M x 128] @ W[128 x 128]; H16OUT selects f32 or fp16 output
#define GBM 64
template <bool H16OUT>
__global__ __launch_bounds__(256) void k_gemm128(const float* __restrict__ X,
                                                 const float* __restrict__ W,
                                                 void* __restrict__ C, int M) {
  __shared__ float sX[GBM][DIM];
  int t = threadIdx.x;
  long bm = (long)blockIdx.x * GBM;
  int rows = min(GBM, M - (int)bm);
  {
    const float4* Xv = (const float4*)(X + bm * DIM);
    float4* sXv = (float4*)&sX[0][0];
    int n4 = rows * DIM / 4;
    for (int i = t; i < n4; i += 256) sXv[i] = Xv[i];
  }
  __syncthreads();
  int c = t & 31;
  int r0 = (t >> 5) * 8;
  float acc[8][4] = {};
  for (int k = 0; k < DIM; k += 4) {
    float4 xr[8];
#pragma unroll
    for (int i = 0; i < 8; ++i) xr[i] = *(const float4*)&sX[r0 + i][k];
#pragma unroll
    for (int kk = 0; kk < 4; ++kk) {
      float w0 = W[(k + kk) * DIM + c];
      float w1 = W[(k + kk) * DIM + c + 32];
      float w2 = W[(k + kk) * DIM + c + 64];
      float w3 = W[(k + kk) * DIM + c + 96];
#pragma unroll
      for (int i = 0; i < 8; ++i) {
        float x = (&xr[i].x)[kk];
        acc[i][0] = fmaf(x, w0, acc[i][0]);
        acc[i][1] = fmaf(x, w1, acc[i][1]);
        acc[i][2] = fmaf(x, w2, acc[i][2]);
        acc[i][3] = fmaf(x, w3, acc[i][3]);
      }
    }
  }
  for (int i = 0; i < 8; ++i) {
    int r = r0 + i;
    if (r < rows) {
      if (H16OUT) {
        ushort* Cr = (ushort*)C + (bm + r) * DIM;
        Cr[c] = f16rn(acc[i][0]);
        Cr[c + 32] = f16rn(acc[i][1]);
        Cr[c + 64] = f16rn(acc[i][2]);
        Cr[c + 96] = f16rn(acc[i][3]);
      } else {
        float* Cr = (float*)C + (bm + r) * DIM;
        Cr[c] = acc[i][0]; Cr[c + 32] = acc[i][1];
        Cr[c + 64] = acc[i][2]; Cr[c + 96] = acc[i][3];
      }
    }
  }
}

// f32 -> fp16 convert, 8 elems/thread
__global__ __launch_bounds__(256) void k_cvt(const float* __restrict__ in,
                                             uint4* __restrict__ out, int n8) {
  int i = blockIdx.x * blockDim.x + threadIdx.x;
  if (i >= n8) return;
  const float4* in4 = (const float4*)in;
  float4 a = in4[2 * i], b = in4[2 * i + 1];
  uint4 o;
  o.x = (uint)f16rn(a.x) | ((uint)f16rn(a.y) << 16);
  o.y = (uint)f16rn(a.z) | ((uint)f16rn(a.w) << 16);
  o.z = (uint)f16rn(b.x) | ((uint)f16rn(b.y) << 16);
  o.w = (uint)f16rn(b.z) | ((uint)f16rn(b.w) << 16);
  out[i] = o;
}

// bucket scatter: pos = cnt[h]++, ed[h*CAP+pos] = node | (rel<<16)
__global__ void k_scatter(const int* __restrict__ sl, int* __restrict__ cnt,
                          uint* __restrict__ ed) {
  int stride = gridDim.x * blockDim.x;
  for (int e = blockIdx.x * blockDim.x + threadIdx.x; e < N_EDGES_C; e += stride) {
    int node = sl[3 * e + 0];
    int h = sl[3 * e + 1];
    int rel = sl[3 * e + 2];
    int pos = atomicAdd(&cnt[h], 1);
    if (pos < CAP) ed[(size_t)h * CAP + pos] = (uint)node | ((uint)rel << 16);
  }
}

// one wave per hyperedge; 8 groups x 8 lanes; group owns one edge per round,
// lane owns 16 dims. fp16 gathers, f32 accumulate, no softmax-max needed
// (|score| < ~50 << 88 = f32 exp overflow).
#define NG 8
__global__ __launch_bounds__(256) void k_agg(
    const ushort* __restrict__ rh_h, const float* __restrict__ rt,
    const ushort* __restrict__ semt_h, const ushort* __restrict__ ne_h,
    const uint* __restrict__ ed, const int* __restrict__ cnt,
    float* __restrict__ agg) {
  int wave = threadIdx.x >> 6;
  int lane = threadIdx.x & 63;
  int h = blockIdx.x * 4 + wave;
  int g = lane >> 3;        // group = edge slot
  int pos = lane & 7;       // dim chunk [pos*16, pos*16+16)
  int d0 = pos * 16;
  const float4* tbp = (const float4*)&rt[(size_t)h * DIM + d0];
  float4 tb0 = tbp[0], tb1 = tbp[1], tb2 = tbp[2], tb3 = tbp[3];
  size_t base = (size_t)h * CAP;
  int n = min(cnt[h], CAP);
  float l = 0.0f;
  float4 a0 = {0,0,0,0}, a1 = {0,0,0,0}, a2 = {0,0,0,0}, a3 = {0,0,0,0};
  const float C2 = 2.8853900817779268f;  // 2*log2(e)

  for (int e = g; e < n; e += NG) {
    uint q = ed[base + e];
    int node = (int)(q & 0xffffu);
    int rel = (int)(q >> 16);
    const uint4* hp = (const uint4*)(rh_h + (size_t)node * DIM + d0);
    const uint4* sp = (const uint4*)(semt_h + (size_t)rel * DIM + d0);
    const uint4* np = (const uint4*)(ne_h + (size_t)node * DIM + d0);
    uint4 ha = hp[0], hb = hp[1];
    uint4 sa = sp[0], sb = sp[1];
    uint4 na = np[0], nb = np[1];
    float da = 0.f, db = 0.f;
#define PAIR(T0, T1, US, UH)                           \
    {                                                  \
      float x0 = T0 + f16lo(US), x1 = T1 + f16hi(US);  \
      float e0 = exp2f(x0 * C2), e1 = exp2f(x1 * C2);  \
      float r0 = __builtin_amdgcn_rcpf(e0 + 1.0f);     \
      float r1 = __builtin_amdgcn_rcpf(e1 + 1.0f);     \
      float t0 = fmaf(-2.0f, r0, 1.0f);                \
      float t1 = fmaf(-2.0f, r1, 1.0f);                \
      da = fmaf(f16lo(UH), t0, da);                    \
      db = fmaf(f16hi(UH), t1, db);                    \
    }
    PAIR(tb0.x, tb0.y, sa.x, ha.x)
    PAIR(tb0.z, tb0.w, sa.y, ha.y)
    PAIR(tb1.x, tb1.y, sa.z, ha.z)
    PAIR(tb1.z, tb1.w, sa.w, ha.w)
    PAIR(tb2.x, tb2.y, sb.x, hb.x)
    PAIR(tb2.z, tb2.w, sb.y, hb.y)
    PAIR(tb3.x, tb3.y, sb.z, hb.z)
    PAIR(tb3.z, tb3.w, sb.w, hb.w)
#undef PAIR
    float dot = da + db;
    dot += __shfl_xor(dot, 1, 64);
    dot += __shfl_xor(dot, 2, 64);
    dot += __shfl_xor(dot, 4, 64);
    float p = __expf(dot);
    l += p;
    a0.x = fmaf(p, f16lo(na.x), a0.x); a0.y = fmaf(p, f16hi(na.x), a0.y);
    a0.z = fmaf(p, f16lo(na.y), a0.z); a0.w = fmaf(p, f16hi(na.y), a0.w);
    a1.x = fmaf(p, f16lo(na.z), a1.x); a1.y = fmaf(p, f16hi(na.z), a1.y);
    a1.z = fmaf(p, f16lo(na.w), a1.z); a1.w = fmaf(p, f16hi(na.w), a1.w);
    a2.x = fmaf(p, f16lo(nb.x), a2.x); a2.y = fmaf(p, f16hi(nb.x), a2.y);
    a2.z = fmaf(p, f16lo(nb.y), a2.z); a2.w = fmaf(p, f16hi(nb.y), a2.w);
    a3.x = fmaf(p, f16lo(nb.z), a3.x); a3.y = fmaf(p, f16hi(nb.z), a3.y);
    a3.z = fmaf(p, f16lo(nb.w), a3.z); a3.w = fmaf(p, f16hi(nb.w), a3.w);
  }
  // merge the 8 groups (lane bits 3,4,5): 17 values x 3 xor steps
#pragma unroll
  for (int mo = 8; mo < 64; mo <<= 1) {
    l += __shfl_xor(l, mo, 64);
    a0.x += __shfl_xor(a0.x, mo, 64); a0.y += __shfl_xor(a0.y, mo, 64);
    a0.z += __shfl_xor(a0.z, mo, 64); a0.w += __shfl_xor(a0.w, mo, 64);
    a1.x += __shfl_xor(a1.x, mo, 64); a1.y += __shfl_xor(a1.y, mo, 64);
    a1.z += __shfl_xor(a1.z, mo, 64); a1.w += __shfl_xor(a1.w, mo, 64);
    a2.x += __shfl_xor(a2.x, mo, 64); a2.y += __shfl_xor(a2.y, mo, 64);
    a2.z += __shfl_xor(a2.z, mo, 64); a2.w += __shfl_xor(a2.w, mo, 64);
    a3.x += __shfl_xor(a3.x, mo, 64); a3.y += __shfl_xor(a3.y, mo, 64);
    a3.z += __shfl_xor(a3.z, mo, 64); a3.w += __shfl_xor(a3.w, mo, 64);
  }
  if (g == 0) {
    float inv = (l > 0.0f) ? __builtin_amdgcn_rcpf(l) : 0.0f;
    float4* op = (float4*)&agg[(size_t)h * DIM + d0];
    float4 o0 = {a0.x * inv, a0.y * inv, a0.z * inv, a0.w * inv};
    float4 o1 = {a1.x * inv, a1.y * inv, a1.z * inv, a1.w * inv};
    float4 o2 = {a2.x * inv, a2.y * inv, a2.z * inv, a2.w * inv};
    float4 o3 = {a3.x * inv, a3.y * inv, a3.z * inv, a3.w * inv};
    op[0] = o0; op[1] = o1; op[2] = o2; op[3] = o3;
  }
}

__global__ void k_transpose128(const float* __restrict__ A, float* __restrict__ B) {
  int i = blockIdx.x * blockDim.x + threadIdx.x;
  if (i < DIM * DIM) {
    int j = i / DIM, k = i % DIM;
    B[k * DIM + j] = A[i];
  }
}

// fused: C = X @ W; out = LN(leakyrelu(C + bias)) * gamma + beta
__global__ __launch_bounds__(256) void k_gemm_ln(
    const float* __restrict__ X, const float* __restrict__ W,
    const float* __restrict__ bias, const float* __restrict__ gamma,
    const float* __restrict__ beta, float* __restrict__ out, int M) {
  __shared__ float sX[GBM][DIM];
  int t = threadIdx.x;
  long bm = (long)blockIdx.x * GBM;
  int rows = min(GBM, M - (int)bm);
  {
    const float4* Xv = (const float4*)(X + bm * DIM);
    float4* sXv = (float4*)&sX[0][0];
    int n4 = rows * DIM / 4;
    for (int i = t; i < n4; i += 256) sXv[i] = Xv[i];
  }
  __syncthreads();
  int c = t & 31;
  int r0 = (t >> 5) * 8;
  float acc[8][4] = {};
  for (int k = 0; k < DIM; k += 4) {
    float4 xr[8];
#pragma unroll
    for (int i = 0; i < 8; ++i) xr[i] = *(const float4*)&sX[r0 + i][k];
#pragma unroll
    for (int kk = 0; kk < 4; ++kk) {
      float w0 = W[(k + kk) * DIM + c];
      float w1 = W[(k + kk) * DIM + c + 32];
      float w2 = W[(k + kk) * DIM + c + 64];
      float w3 = W[(k + kk) * DIM + c + 96];
#pragma unroll
      for (int i = 0; i < 8; ++i) {
        float x = (&xr[i].x)[kk];
        acc[i][0] = fmaf(x, w0, acc[i][0]);
        acc[i][1] = fmaf(x, w1, acc[i][1]);
        acc[i][2] = fmaf(x, w2, acc[i][2]);
        acc[i][3] = fmaf(x, w3, acc[i][3]);
      }
    }
  }
  float b0 = bias[c], b1 = bias[c + 32], b2 = bias[c + 64], b3 = bias[c + 96];
  float g0 = gamma[c], g1 = gamma[c + 32], g2 = gamma[c + 64], g3 = gamma[c + 96];
  float e0 = beta[c], e1 = beta[c + 32], e2 = beta[c + 64], e3 = beta[c + 96];
#pragma unroll
  for (int i = 0; i < 8; ++i) {
    float v0 = acc[i][0] + b0, v1 = acc[i][1] + b1;
    float v2 = acc[i][2] + b2, v3 = acc[i][3] + b3;
    v0 = v0 >= 0.0f ? v0 : 0.01f * v0;
    v1 = v1 >= 0.0f ? v1 : 0.01f * v1;
    v2 = v2 >= 0.0f ? v2 : 0.01f * v2;
    v3 = v3 >= 0.0f ? v3 : 0.01f * v3;
    float mu = half_sum32(v0 + v1 + v2 + v3) * (1.0f / 128.0f);
    float d0 = v0 - mu, d1 = v1 - mu, d2 = v2 - mu, d3 = v3 - mu;
    float var = half_sum32(d0 * d0 + d1 * d1 + d2 * d2 + d3 * d3) * (1.0f / 128.0f);
    float inv = rsqrtf(var + 1e-5f);
    int r = r0 + i;
    if (r < rows) {
      float* Or = out + (bm + r) * DIM;
      Or[c] = d0 * inv * g0 + e0;
      Or[c + 32] = d1 * inv * g1 + e1;
      Or[c + 64] = d2 * inv * g2 + e2;
      Or[c + 96] = d3 * inv * g3 + e3;
    }
  }
}

extern "C" void kernel_launch(void* const* d_in, const int* in_sizes, int n_in,
                              void* d_out, int out_size, void* d_ws, size_t ws_size,
                              hipStream_t stream) {
  const float* node_emb = (const float*)d_in[0];
  const float* sem_emb = (const float*)d_in[1];
  const float* hyper_emb = (const float*)d_in[2];
  const float* W_r = (const float*)d_in[3];
  const float* lin_w = (const float*)d_in[4];
  const float* lin_b = (const float*)d_in[5];
  const float* sem_w = (const float*)d_in[6];
  const float* sem_b = (const float*)d_in[7];
  const float* ln_g = (const float*)d_in[8];
  const float* ln_b = (const float*)d_in[9];
  const int* sl = (const int*)d_in[10];
  float* out = (float*)d_out;

  float* ws = (float*)d_ws;
  float* rt = ws;                            // 2,560,000 f32
  float* aggb = rt + 2560000;                // 2,560,000 f32
  float* linwT = aggb + 2560000;             // 16,384 f32
  int* cnt = (int*)(linwT + 16384);          // 20,000
  uint* ed = (uint*)(cnt + 20000);           // 2,560,000 u32
  ushort* rh_h = (ushort*)(ed + 2560000);    // 6,400,000 fp16
  ushort* ne_h = rh_h + 6400000;             // 6,400,000 fp16
  ushort* semt_h = ne_h + 6400000;           // 32,768 fp16

  hipMemsetAsync(cnt, 0, sizeof(int) * 20000, stream);
  k_sem<<<N_REL, 128, 0, stream>>>(sem_emb, sem_w, sem_b, semt_h);
  k_gemm128<false><<<(N_HYPER + GBM - 1) / GBM, 256, 0, stream>>>(hyper_emb, W_r, rt, N_HYPER);
  k_gemm128<true><<<(N_NODES + GBM - 1) / GBM, 256, 0, stream>>>(node_emb, W_r, rh_h, N_NODES);
  k_cvt<<<(N_NODES * DIM / 8 + 255) / 256, 256, 0, stream>>>(node_emb, (uint4*)ne_h, N_NODES * DIM / 8);
  k_scatter<<<2048, 256, 0, stream>>>(sl, cnt, ed);
  k_agg<<<N_HYPER / 4, 256, 0, stream>>>(rh_h, rt, semt_h, ne_h, ed, cnt, aggb);
  k_transpose128<<<64, 256, 0, stream>>>(lin_w, linwT);
  k_gemm_ln<<<(N_HYPER + GBM - 1) / GBM, 256, 0, stream>>>(aggb, linwT, lin_b, ln_g, ln_b, out, N_HYPER);
}

// Round 7
// 302.174 us; speedup vs baseline: 1.3160x; 1.0722x over previous
//
#include <hip/hip_runtime.h>
#include <hip/hip_bf16.h>
#include <hip/hip_fp16.h>
#include <math.h>

#define N_NODES 50000
#define N_HYPER 20000
#define N_EDGES_C 1000000
#define N_REL 256
#define DIM 128
#define SEM_DIM 64
#define CAP 128   // max edges per bucket; mean=50, sigma~7 -> ~11 sigma headroom

typedef unsigned int uint;
typedef unsigned short ushort;
typedef _Float16 v2h __attribute__((ext_vector_type(2)));

#define SC_2L2E 2.8853900817779268f   // 2*log2(e): exp(2x) = exp2(x*SC)
#define SC_L2E  1.4426950408889634f   // log2(e):   exp(s)  = exp2(s*SC)

__device__ inline float half_sum32(float v) {
#pragma unroll
  for (int m = 1; m < 32; m <<= 1) v += __shfl_xor(v, m, 64);
  return v;
}

__device__ inline ushort f16rn(float f) { return __half_as_ushort(__float2half_rn(f)); }
__device__ inline __half2 u2h2(uint u) { return __builtin_bit_cast(__half2, u); }

__device__ inline float fdot2(__half2 a, __half2 b, float c) {
#if __has_builtin(__builtin_amdgcn_fdot2)
  return __builtin_amdgcn_fdot2(__builtin_bit_cast(v2h, a),
                                __builtin_bit_cast(v2h, b), c, false);
#else
  float2 fa = __half22float2(a), fb = __half22float2(b);
  return fmaf(fa.x, fb.x, fmaf(fa.y, fb.y, c));
#endif
}

// sem_t_h[r][j] = fp16( (sem_b[j] + sum_k emb[r][k]*sem_w[j][k]) * 2log2e )
__global__ __launch_bounds__(128) void k_sem(const float* __restrict__ emb,
                                             const float* __restrict__ sem_w,
                                             const float* __restrict__ sem_b,
                                             ushort* __restrict__ sem_t_h) {
  __shared__ float sW[DIM][SEM_DIM + 1];
  __shared__ float sE[SEM_DIM];
  int t = threadIdx.x;
  for (int i = t; i < DIM * SEM_DIM; i += 128) sW[i / SEM_DIM][i % SEM_DIM] = sem_w[i];
  int r = blockIdx.x;
  if (t < SEM_DIM) sE[t] = emb[r * SEM_DIM + t];
  __syncthreads();
  float acc = sem_b[t];
#pragma unroll 8
  for (int k = 0; k < SEM_DIM; ++k) acc = fmaf(sE[k], sW[t][k], acc);
  sem_t_h[r * DIM + t] = f16rn(acc * SC_2L2E);
}

// rt[M x 128] = X @ W, f32 out (for the tb operand, read once per wave)
#define GBM 64
__global__ __launch_bounds__(256) void k_gemm_f32(const float* __restrict__ X,
                                                  const float* __restrict__ W,
                                                  float* __restrict__ C, int M) {
  __shared__ float sX[GBM][DIM];
  int t = threadIdx.x;
  long bm = (long)blockIdx.x * GBM;
  int rows = min(GBM, M - (int)bm);
  {
    const float4* Xv = (const float4*)(X + bm * DIM);
    float4* sXv = (float4*)&sX[0][0];
    int n4 = rows * DIM / 4;
    for (int i = t; i < n4; i += 256) sXv[i] = Xv[i];
  }
  __syncthreads();
  int c = t & 31;
  int r0 = (t >> 5) * 8;
  float acc[8][4] = {};
  for (int k = 0; k < DIM; k += 4) {
    float4 xr[8];
#pragma unroll
    for (int i = 0; i < 8; ++i) xr[i] = *(const float4*)&sX[r0 + i][k];
#pragma unroll
    for (int kk = 0; kk < 4; ++kk) {
      float w0 = W[(k + kk) * DIM + c];
      float w1 = W[(k + kk) * DIM + c + 32];
      float w2 = W[(k + kk) * DIM + c + 64];
      float w3 = W[(k + kk) * DIM + c + 96];
#pragma unroll
      for (int i = 0; i < 8; ++i) {
        float x = (&xr[i].x)[kk];
        acc[i][0] = fmaf(x, w0, acc[i][0]);
        acc[i][1] = fmaf(x, w1, acc[i][1]);
        acc[i][2] = fmaf(x, w2, acc[i][2]);
        acc[i][3] = fmaf(x, w3, acc[i][3]);
      }
    }
  }
  for (int i = 0; i < 8; ++i) {
    int r = r0 + i;
    if (r < rows) {
      float* Cr = C + (bm + r) * DIM;
      Cr[c] = acc[i][0]; Cr[c + 32] = acc[i][1];
      Cr[c + 64] = acc[i][2]; Cr[c + 96] = acc[i][3];
    }
  }
}

// rh_h[M x 128] = fp16((X @ W) * log2e); ne_h = fp16(X)  (fused convert from LDS)
__global__ __launch_bounds__(256) void k_gemm_node(const float* __restrict__ X,
                                                   const float* __restrict__ W,
                                                   ushort* __restrict__ rh_h,
                                                   ushort* __restrict__ ne_h, int M) {
  __shared__ float sX[GBM][DIM];
  int t = threadIdx.x;
  long bm = (long)blockIdx.x * GBM;
  int rows = min(GBM, M - (int)bm);
  {
    const float4* Xv = (const float4*)(X + bm * DIM);
    float4* sXv = (float4*)&sX[0][0];
    int n4 = rows * DIM / 4;
    for (int i = t; i < n4; i += 256) sXv[i] = Xv[i];
  }
  __syncthreads();
  int c = t & 31;
  int r0 = (t >> 5) * 8;
  float acc[8][4] = {};
  for (int k = 0; k < DIM; k += 4) {
    float4 xr[8];
#pragma unroll
    for (int i = 0; i < 8; ++i) xr[i] = *(const float4*)&sX[r0 + i][k];
#pragma unroll
    for (int kk = 0; kk < 4; ++kk) {
      float w0 = W[(k + kk) * DIM + c];
      float w1 = W[(k + kk) * DIM + c + 32];
      float w2 = W[(k + kk) * DIM + c + 64];
      float w3 = W[(k + kk) * DIM + c + 96];
#pragma unroll
      for (int i = 0; i < 8; ++i) {
        float x = (&xr[i].x)[kk];
        acc[i][0] = fmaf(x, w0, acc[i][0]);
        acc[i][1] = fmaf(x, w1, acc[i][1]);
        acc[i][2] = fmaf(x, w2, acc[i][2]);
        acc[i][3] = fmaf(x, w3, acc[i][3]);
      }
    }
  }
  for (int i = 0; i < 8; ++i) {
    int r = r0 + i;
    if (r < rows) {
      ushort* Cr = rh_h + (bm + r) * DIM;
      Cr[c] = f16rn(acc[i][0] * SC_L2E);
      Cr[c + 32] = f16rn(acc[i][1] * SC_L2E);
      Cr[c + 64] = f16rn(acc[i][2] * SC_L2E);
      Cr[c + 96] = f16rn(acc[i][3] * SC_L2E);
    }
  }
  // fused node_emb -> fp16 convert straight out of LDS (saves the k_cvt pass)
  uint* nh = (uint*)ne_h + bm * (DIM / 2);
  int nu = rows * (DIM / 2);
  for (int i = t; i < nu; i += 256) {
    int r = i >> 6, j = (i & 63) * 2;
    nh[i] = (uint)f16rn(sX[r][j]) | ((uint)f16rn(sX[r][j + 1]) << 16);
  }
}

// bucket scatter: pos = cnt[h]++, ed[h*CAP+pos] = node | (rel<<16)
__global__ void k_scatter(const int* __restrict__ sl, int* __restrict__ cnt,
                          uint* __restrict__ ed) {
  int stride = gridDim.x * blockDim.x;
  for (int e = blockIdx.x * blockDim.x + threadIdx.x; e < N_EDGES_C; e += stride) {
    int node = sl[3 * e + 0];
    int h = sl[3 * e + 1];
    int rel = sl[3 * e + 2];
    int pos = atomicAdd(&cnt[h], 1);
    if (pos < CAP) ed[(size_t)h * CAP + pos] = (uint)node | ((uint)rel << 16);
  }
}

// one wave per hyperedge (2 waves/block); 8 groups x 8 lanes; group owns one
// edge per round, lane owns 16 dims. Packed-fp16 tanh pipeline + v_dot2,
// prescaled operands (exp2-direct), f32 accumulate, no softmax-max needed.
#define NG 8
#define BLK_H 2
__global__ __launch_bounds__(128) void k_agg(
    const ushort* __restrict__ rh_h, const float* __restrict__ rt,
    const ushort* __restrict__ semt_h, const ushort* __restrict__ ne_h,
    const uint* __restrict__ ed, const int* __restrict__ cnt,
    float* __restrict__ agg) {
  int wave = threadIdx.x >> 6;
  int lane = threadIdx.x & 63;
  int h = blockIdx.x * BLK_H + wave;
  int g = lane >> 3;        // group = edge slot
  int pos = lane & 7;       // dim chunk [pos*16, pos*16+16)
  int d0 = pos * 16;
  // tb' = fp16(rt * 2log2e), packed pairs
  const float4* tbp = (const float4*)&rt[(size_t)h * DIM + d0];
  float4 tf0 = tbp[0], tf1 = tbp[1], tf2 = tbp[2], tf3 = tbp[3];
  __half2 tb0 = __floats2half2_rn(tf0.x * SC_2L2E, tf0.y * SC_2L2E);
  __half2 tb1 = __floats2half2_rn(tf0.z * SC_2L2E, tf0.w * SC_2L2E);
  __half2 tb2 = __floats2half2_rn(tf1.x * SC_2L2E, tf1.y * SC_2L2E);
  __half2 tb3 = __floats2half2_rn(tf1.z * SC_2L2E, tf1.w * SC_2L2E);
  __half2 tb4 = __floats2half2_rn(tf2.x * SC_2L2E, tf2.y * SC_2L2E);
  __half2 tb5 = __floats2half2_rn(tf2.z * SC_2L2E, tf2.w * SC_2L2E);
  __half2 tb6 = __floats2half2_rn(tf3.x * SC_2L2E, tf3.y * SC_2L2E);
  __half2 tb7 = __floats2half2_rn(tf3.z * SC_2L2E, tf3.w * SC_2L2E);
  const __half2 one2 = __floats2half2_rn(1.0f, 1.0f);
  const __half2 m2 = __floats2half2_rn(-2.0f, -2.0f);
  size_t base = (size_t)h * CAP;
  int n = min(cnt[h], CAP);
  float l = 0.0f;
  float4 a0 = {0,0,0,0}, a1 = {0,0,0,0}, a2 = {0,0,0,0}, a3 = {0,0,0,0};

  for (int e = g; e < n; e += NG) {
    uint q = ed[base + e];
    int node = (int)(q & 0xffffu);
    int rel = (int)(q >> 16);
    const uint4* hp = (const uint4*)(rh_h + (size_t)node * DIM + d0);
    const uint4* sp = (const uint4*)(semt_h + (size_t)rel * DIM + d0);
    const uint4* np = (const uint4*)(ne_h + (size_t)node * DIM + d0);
    uint4 ha = hp[0], hb = hp[1];
    uint4 sa = sp[0], sb = sp[1];
    uint4 na = np[0], nb = np[1];
    float da = 0.0f, db = 0.0f;
    // tanh(arg/SC) where arg = tb'+st' (fp16 packed, prescaled by 2log2e):
    //   e = exp2(arg); t = 1 - 2/(e+1); saturates correctly via f16 inf/0.
#define TP(US, UH, TB, ACC)                      \
    {                                            \
      __half2 arg = __hadd2(TB, u2h2(US));       \
      __half2 e2 = h2exp2(arg);                  \
      __half2 r2 = h2rcp(__hadd2(e2, one2));     \
      __half2 t2 = __hfma2(m2, r2, one2);        \
      ACC = fdot2(u2h2(UH), t2, ACC);            \
    }
    TP(sa.x, ha.x, tb0, da) TP(sa.y, ha.y, tb1, db)
    TP(sa.z, ha.z, tb2, da) TP(sa.w, ha.w, tb3, db)
    TP(sb.x, hb.x, tb4, da) TP(sb.y, hb.y, tb5, db)
    TP(sb.z, hb.z, tb6, da) TP(sb.w, hb.w, tb7, db)
#undef TP
    float dot = da + db;   // = score * log2e (rh prescaled)
    dot += __shfl_xor(dot, 1, 64);
    dot += __shfl_xor(dot, 2, 64);
    dot += __shfl_xor(dot, 4, 64);
    float p = exp2f(dot);
    l += p;
    float2 n0 = __half22float2(u2h2(na.x));
    float2 n1 = __half22float2(u2h2(na.y));
    float2 n2 = __half22float2(u2h2(na.z));
    float2 n3 = __half22float2(u2h2(na.w));
    float2 n4 = __half22float2(u2h2(nb.x));
    float2 n5 = __half22float2(u2h2(nb.y));
    float2 n6 = __half22float2(u2h2(nb.z));
    float2 n7 = __half22float2(u2h2(nb.w));
    a0.x = fmaf(p, n0.x, a0.x); a0.y = fmaf(p, n0.y, a0.y);
    a0.z = fmaf(p, n1.x, a0.z); a0.w = fmaf(p, n1.y, a0.w);
    a1.x = fmaf(p, n2.x, a1.x); a1.y = fmaf(p, n2.y, a1.y);
    a1.z = fmaf(p, n3.x, a1.z); a1.w = fmaf(p, n3.y, a1.w);
    a2.x = fmaf(p, n4.x, a2.x); a2.y = fmaf(p, n4.y, a2.y);
    a2.z = fmaf(p, n5.x, a2.z); a2.w = fmaf(p, n5.y, a2.w);
    a3.x = fmaf(p, n6.x, a3.x); a3.y = fmaf(p, n6.y, a3.y);
    a3.z = fmaf(p, n7.x, a3.z); a3.w = fmaf(p, n7.y, a3.w);
  }
  // merge the 8 groups (lane bits 3,4,5): 17 values x 3 xor steps
#pragma unroll
  for (int mo = 8; mo < 64; mo <<= 1) {
    l += __shfl_xor(l, mo, 64);
    a0.x += __shfl_xor(a0.x, mo, 64); a0.y += __shfl_xor(a0.y, mo, 64);
    a0.z += __shfl_xor(a0.z, mo, 64); a0.w += __shfl_xor(a0.w, mo, 64);
    a1.x += __shfl_xor(a1.x, mo, 64); a1.y += __shfl_xor(a1.y, mo, 64);
    a1.z += __shfl_xor(a1.z, mo, 64); a1.w += __shfl_xor(a1.w, mo, 64);
    a2.x += __shfl_xor(a2.x, mo, 64); a2.y += __shfl_xor(a2.y, mo, 64);
    a2.z += __shfl_xor(a2.z, mo, 64); a2.w += __shfl_xor(a2.w, mo, 64);
    a3.x += __shfl_xor(a3.x, mo, 64); a3.y += __shfl_xor(a3.y, mo, 64);
    a3.z += __shfl_xor(a3.z, mo, 64); a3.w += __shfl_xor(a3.w, mo, 64);
  }
  if (g == 0) {
    float inv = (l > 0.0f) ? __builtin_amdgcn_rcpf(l) : 0.0f;
    float4* op = (float4*)&agg[(size_t)h * DIM + d0];
    float4 o0 = {a0.x * inv, a0.y * inv, a0.z * inv, a0.w * inv};
    float4 o1 = {a1.x * inv, a1.y * inv, a1.z * inv, a1.w * inv};
    float4 o2 = {a2.x * inv, a2.y * inv, a2.z * inv, a2.w * inv};
    float4 o3 = {a3.x * inv, a3.y * inv, a3.z * inv, a3.w * inv};
    op[0] = o0; op[1] = o1; op[2] = o2; op[3] = o3;
  }
}

__global__ void k_transpose128(const float* __restrict__ A, float* __restrict__ B) {
  int i = blockIdx.x * blockDim.x + threadIdx.x;
  if (i < DIM * DIM) {
    int j = i / DIM, k = i % DIM;
    B[k * DIM + j] = A[i];
  }
}

// fused: C = X @ W; out = LN(leakyrelu(C + bias)) * gamma + beta
__global__ __launch_bounds__(256) void k_gemm_ln(
    const float* __restrict__ X, const float* __restrict__ W,
    const float* __restrict__ bias, const float* __restrict__ gamma,
    const float* __restrict__ beta, float* __restrict__ out, int M) {
  __shared__ float sX[GBM][DIM];
  int t = threadIdx.x;
  long bm = (long)blockIdx.x * GBM;
  int rows = min(GBM, M - (int)bm);
  {
    const float4* Xv = (const float4*)(X + bm * DIM);
    float4* sXv = (float4*)&sX[0][0];
    int n4 = rows * DIM / 4;
    for (int i = t; i < n4; i += 256) sXv[i] = Xv[i];
  }
  __syncthreads();
  int c = t & 31;
  int r0 = (t >> 5) * 8;
  float acc[8][4] = {};
  for (int k = 0; k < DIM; k += 4) {
    float4 xr[8];
#pragma unroll
    for (int i = 0; i < 8; ++i) xr[i] = *(const float4*)&sX[r0 + i][k];
#pragma unroll
    for (int kk = 0; kk < 4; ++kk) {
      float w0 = W[(k + kk) * DIM + c];
      float w1 = W[(k + kk) * DIM + c + 32];
      float w2 = W[(k + kk) * DIM + c + 64];
      float w3 = W[(k + kk) * DIM + c + 96];
#pragma unroll
      for (int i = 0; i < 8; ++i) {
        float x = (&xr[i].x)[kk];
        acc[i][0] = fmaf(x, w0, acc[i][0]);
        acc[i][1] = fmaf(x, w1, acc[i][1]);
        acc[i][2] = fmaf(x, w2, acc[i][2]);
        acc[i][3] = fmaf(x, w3, acc[i][3]);
      }
    }
  }
  float b0 = bias[c], b1 = bias[c + 32], b2 = bias[c + 64], b3 = bias[c + 96];
  float g0 = gamma[c], g1 = gamma[c + 32], g2 = gamma[c + 64], g3 = gamma[c + 96];
  float e0 = beta[c], e1 = beta[c + 32], e2 = beta[c + 64], e3 = beta[c + 96];
#pragma unroll
  for (int i = 0; i < 8; ++i) {
    float v0 = acc[i][0] + b0, v1 = acc[i][1] + b1;
    float v2 = acc[i][2] + b2, v3 = acc[i][3] + b3;
    v0 = v0 >= 0.0f ? v0 : 0.01f * v0;
    v1 = v1 >= 0.0f ? v1 : 0.01f * v1;
    v2 = v2 >= 0.0f ? v2 : 0.01f * v2;
    v3 = v3 >= 0.0f ? v3 : 0.01f * v3;
    float mu = half_sum32(v0 + v1 + v2 + v3) * (1.0f / 128.0f);
    float d0 = v0 - mu, d1 = v1 - mu, d2 = v2 - mu, d3 = v3 - mu;
    float var = half_sum32(d0 * d0 + d1 * d1 + d2 * d2 + d3 * d3) * (1.0f / 128.0f);
    float inv = rsqrtf(var + 1e-5f);
    int r = r0 + i;
    if (r < rows) {
      float* Or = out + (bm + r) * DIM;
      Or[c] = d0 * inv * g0 + e0;
      Or[c + 32] = d1 * inv * g1 + e1;
      Or[c + 64] = d2 * inv * g2 + e2;
      Or[c + 96] = d3 * inv * g3 + e3;
    }
  }
}

extern "C" void kernel_launch(void* const* d_in, const int* in_sizes, int n_in,
                              void* d_out, int out_size, void* d_ws, size_t ws_size,
                              hipStream_t stream) {
  const float* node_emb = (const float*)d_in[0];
  const float* sem_emb = (const float*)d_in[1];
  const float* hyper_emb = (const float*)d_in[2];
  const float* W_r = (const float*)d_in[3];
  const float* lin_w = (const float*)d_in[4];
  const float* lin_b = (const float*)d_in[5];
  const float* sem_w = (const float*)d_in[6];
  const float* sem_b = (const float*)d_in[7];
  const float* ln_g = (const float*)d_in[8];
  const float* ln_b = (const float*)d_in[9];
  const int* sl = (const int*)d_in[10];
  float* out = (float*)d_out;

  float* ws = (float*)d_ws;
  float* rt = ws;                            // 2,560,000 f32
  float* aggb = rt + 2560000;                // 2,560,000 f32
  float* linwT = aggb + 2560000;             // 16,384 f32
  int* cnt = (int*)(linwT + 16384);          // 20,000
  uint* ed = (uint*)(cnt + 20000);           // 2,560,000 u32
  ushort* rh_h = (ushort*)(ed + 2560000);    // 6,400,000 fp16 (prescaled log2e)
  ushort* ne_h = rh_h + 6400000;             // 6,400,000 fp16
  ushort* semt_h = ne_h + 6400000;           // 32,768 fp16 (prescaled 2log2e)

  hipMemsetAsync(cnt, 0, sizeof(int) * 20000, stream);
  k_sem<<<N_REL, 128, 0, stream>>>(sem_emb, sem_w, sem_b, semt_h);
  k_gemm_f32<<<(N_HYPER + GBM - 1) / GBM, 256, 0, stream>>>(hyper_emb, W_r, rt, N_HYPER);
  k_gemm_node<<<(N_NODES + GBM - 1) / GBM, 256, 0, stream>>>(node_emb, W_r, rh_h, ne_h, N_NODES);
  k_scatter<<<2048, 256, 0, stream>>>(sl, cnt, ed);
  k_agg<<<N_HYPER / BLK_H, 128, 0, stream>>>(rh_h, rt, semt_h, ne_h, ed, cnt, aggb);
  k_transpose128<<<64, 256, 0, stream>>>(lin_w, linwT);
  k_gemm_ln<<<(N_HYPER + GBM - 1) / GBM, 256, 0, stream>>>(aggb, linwT, lin_b, ln_g, ln_b, out, N_HYPER);
}